// Round 5
// baseline (212.256 us; speedup 1.0000x reference)
//
#include <hip/hip_runtime.h>
#include <hip/hip_bf16.h>

// Problem constants (set_attention): B=4, Nq=Nk=2048, D_IN=512, H=8, HS=64
#define BB   4
#define NQ   2048
#define NKK  2048
#define DIN  512
#define NH   8
#define HS   64
#define HD   512  // NH*HS

typedef __hip_bfloat16 bf16;
typedef unsigned short ushort_t;
typedef __attribute__((ext_vector_type(8))) short short8;   // 8 bf16 (4 VGPRs)
typedef __attribute__((ext_vector_type(4))) float f32x4;    // MFMA 16x16 C/D
typedef __attribute__((ext_vector_type(16))) float f32x16;  // MFMA 32x32 C/D
typedef __attribute__((ext_vector_type(4))) unsigned u32x4;

__device__ __forceinline__ unsigned short f2bu(float x) {
  bf16 h = __float2bfloat16(x);
  return *(unsigned short*)&h;
}

// ---------------------------------------------------------------------------
// Kernel 0: weight transpose + bf16 convert.
// z<3:  W[512k][512n] f32 -> Wt_z[n][k] bf16   (64x64 tiles via LDS)
// z==3: Wh[512k][64n] f32 -> Wht[n][k] bf16
// ---------------------------------------------------------------------------
__global__ __launch_bounds__(256) void wtrans_kernel(
    const float* __restrict__ Wq, const float* __restrict__ Wk,
    const float* __restrict__ Wv, const float* __restrict__ Wh,
    ushort_t* __restrict__ Wt, ushort_t* __restrict__ Wht) {
  const int z = blockIdx.z;
  const float* src;
  ushort_t* dst;
  int S;  // source row length (n-dim)
  if (z < 3) {
    src = (z == 0) ? Wq : (z == 1) ? Wk : Wv;
    dst = Wt + (size_t)z * 512 * 512;
    S = 512;
  } else {
    if (blockIdx.y != 0) return;
    src = Wh;
    dst = Wht;
    S = 64;
  }
  const int k0 = blockIdx.x * 64;
  const int n0 = (z < 3) ? blockIdx.y * 64 : 0;

  __shared__ ushort_t Ls[64 * 72];
  const int tid = threadIdx.x;
  {
    int r = tid >> 2, cb = (tid & 3) * 16;
    const float* sp = src + (size_t)(k0 + r) * S + n0 + cb;
#pragma unroll
    for (int ii = 0; ii < 4; ++ii) {
      float4 f = *(const float4*)(sp + ii * 4);
      __align__(8) ushort_t t4[4] = {f2bu(f.x), f2bu(f.y), f2bu(f.z), f2bu(f.w)};
      *(uint2*)(&Ls[r * 72 + cb + ii * 4]) = *(uint2*)t4;
    }
  }
  __syncthreads();
  {
    int rr = tid >> 2, tb = (tid & 3) * 16;
    __align__(16) ushort_t tmp[16];
#pragma unroll
    for (int j = 0; j < 16; ++j) tmp[j] = Ls[(tb + j) * 72 + rr];
    ushort_t* dp = dst + (size_t)(n0 + rr) * 512 + k0 + tb;
    *(int4*)dp       = ((int4*)tmp)[0];
    *(int4*)(dp + 8) = ((int4*)tmp)[1];
  }
}

// ---------------------------------------------------------------------------
// Kernel 1: QKV projections, bf16 MFMA, double-buffered. Y = X @ W.
// Q is scaled by (1/sqrt(64)) * log2(e) so attention can use exp2 directly.
// ---------------------------------------------------------------------------
__global__ __launch_bounds__(256) void proj_kernel(
    const float* __restrict__ q, const float* __restrict__ k,
    const ushort_t* __restrict__ Wt, ushort_t* __restrict__ Qf,
    ushort_t* __restrict__ Kf, ushort_t* __restrict__ Vf) {
  const int z = blockIdx.z;
  const float* X = (z == 0) ? q : k;
  const ushort_t* Wz = Wt + (size_t)z * 512 * 512;
  ushort_t* Y = (z == 0) ? Qf : (z == 1) ? Kf : Vf;
  // fold 1/sqrt(64) AND log2(e) into Q (attn uses exp2)
  const float sc = (z == 0) ? 0.18033688011112042f : 1.0f;

  __shared__ ushort_t As[2 * 128 * 40];  // [buf][m][k]
  __shared__ ushort_t Bs[2 * 128 * 40];  // [buf][n][k]

  const int tid  = threadIdx.x;
  const int lane = tid & 63;
  const int w    = tid >> 6;
  const int quad = lane >> 4;
  const int c    = lane & 15;
  const int wm   = w >> 1, wn = w & 1;

  const int m0 = blockIdx.y * 128;
  const int n0 = blockIdx.x * 128;
  const int sm  = tid >> 1;
  const int skb = (tid & 1) * 16;

  float4 xa[4];
  int4 wb[2];
  auto load_t = [&](int k0) {
    const float* xp = X + (size_t)(m0 + sm) * DIN + k0 + skb;
    xa[0] = *(const float4*)(xp + 0);
    xa[1] = *(const float4*)(xp + 4);
    xa[2] = *(const float4*)(xp + 8);
    xa[3] = *(const float4*)(xp + 12);
    const ushort_t* wp = Wz + (size_t)(n0 + sm) * 512 + k0 + skb;
    wb[0] = *(const int4*)wp;
    wb[1] = *(const int4*)(wp + 8);
  };
  auto store_t = [&](int buf) {
    __align__(16) ushort_t ta[16];
#pragma unroll
    for (int ii = 0; ii < 4; ++ii) {
      ta[ii * 4 + 0] = f2bu(xa[ii].x);
      ta[ii * 4 + 1] = f2bu(xa[ii].y);
      ta[ii * 4 + 2] = f2bu(xa[ii].z);
      ta[ii * 4 + 3] = f2bu(xa[ii].w);
    }
    *(int4*)(&As[buf * 5120 + sm * 40 + skb])     = ((int4*)ta)[0];
    *(int4*)(&As[buf * 5120 + sm * 40 + skb + 8]) = ((int4*)ta)[1];
    *(int4*)(&Bs[buf * 5120 + sm * 40 + skb])     = wb[0];
    *(int4*)(&Bs[buf * 5120 + sm * 40 + skb + 8]) = wb[1];
  };

  f32x4 acc[4][4];
#pragma unroll
  for (int m = 0; m < 4; ++m)
#pragma unroll
    for (int n = 0; n < 4; ++n) acc[m][n] = (f32x4)0.0f;

  load_t(0);
  store_t(0);
  __syncthreads();

  for (int t = 0; t < 16; ++t) {
    const int cur = t & 1;
    if (t < 15) load_t((t + 1) * 32);
    const ushort_t* as = As + cur * 5120;
    const ushort_t* bs = Bs + cur * 5120;
    short8 af[4], bfr[4];
#pragma unroll
    for (int m = 0; m < 4; ++m)
      af[m] = *(const short8*)(&as[(wm * 64 + m * 16 + c) * 40 + quad * 8]);
#pragma unroll
    for (int n = 0; n < 4; ++n)
      bfr[n] = *(const short8*)(&bs[(wn * 64 + n * 16 + c) * 40 + quad * 8]);
#pragma unroll
    for (int m = 0; m < 4; ++m)
#pragma unroll
      for (int n = 0; n < 4; ++n)
        acc[m][n] = __builtin_amdgcn_mfma_f32_16x16x32_bf16(af[m], bfr[n], acc[m][n], 0, 0, 0);
    if (t < 15) store_t(cur ^ 1);
    __syncthreads();
  }

#pragma unroll
  for (int m = 0; m < 4; ++m)
#pragma unroll
    for (int n = 0; n < 4; ++n)
#pragma unroll
      for (int r = 0; r < 4; ++r) {
        int row = m0 + wm * 64 + m * 16 + quad * 4 + r;
        int col = n0 + wn * 64 + n * 16 + c;
        Y[(size_t)row * HD + col] = f2bu(acc[m][n][r] * sc);
      }
}

// ---------------------------------------------------------------------------
// Kernel 1b: V transpose. Vf[(b*2048+t)*512 + cc] -> Vt[(b*512+cc)*2048 + t].
// ---------------------------------------------------------------------------
__global__ __launch_bounds__(256) void vtrans_kernel(
    const ushort_t* __restrict__ Vf, ushort_t* __restrict__ Vt) {
  const int b  = blockIdx.z;
  const int t0 = blockIdx.x * 64;
  const int c0 = blockIdx.y * 64;
  __shared__ ushort_t Ls[64 * 72];
  const int tid = threadIdx.x;
  {
    int r = tid >> 2, cb = (tid & 3) * 16;
    const ushort_t* src = Vf + (size_t)(b * NQ + t0 + r) * HD + c0 + cb;
    *(int4*)(&Ls[r * 72 + cb])     = *(const int4*)src;
    *(int4*)(&Ls[r * 72 + cb + 8]) = *(const int4*)(src + 8);
  }
  __syncthreads();
  {
    int rr = tid >> 2, tb = (tid & 3) * 16;
    __align__(16) ushort_t tmp[16];
#pragma unroll
    for (int j = 0; j < 16; ++j) tmp[j] = Ls[(tb + j) * 72 + rr];
    ushort_t* dst = Vt + (size_t)(b * HD + c0 + rr) * NKK + t0 + tb;
    *(int4*)dst       = ((int4*)tmp)[0];
    *(int4*)(dst + 8) = ((int4*)tmp)[1];
  }
}

// ---------------------------------------------------------------------------
// Kernel 2: MFMA flash attention, v6 — in-block K-split, 2 waves/SIMD.
//  - 4 waves/block (256 thr): wave w = (qp = w&1 -> q panel, kh = w>>1 ->
//    key half). Each wave: 64 q-rows, 1024 keys (16 tiles).
//  - Grid 16x8x4 = 512 blocks, 8 waves/CU = 2 waves/SIMD (vs 1 in v5):
//    hides ds_read/barrier latency that made v5 idle 60% of cycles.
//  - Per-kh K/V LDS double buffers (64 KB); same global_load_lds staging
//    with pre-swizzled source column; reads use slot ^ (row&7).
//  - Epilogue: kh=1 waves dump unnormalized O (f32) + partial row-sums into
//    the dead K/V LDS; kh=0 waves add, normalize by combined denominator,
//    write CTX. Exact f32 combine (no-max softmax makes it associative).
//  - Softmax p = 2^s via __builtin_amdgcn_exp2f (log2e folded into Q scale).
//  - P -> PV A-frag via v_cvt_pk_bf16_f32 + v_permlane32_swap_b32 (T12).
// ---------------------------------------------------------------------------
__global__ __launch_bounds__(256) void attn_kernel(
    const ushort_t* __restrict__ Qf, const ushort_t* __restrict__ Kf,
    const ushort_t* __restrict__ Vt, ushort_t* __restrict__ CTX) {
  const int qb = blockIdx.x;
  const int h  = blockIdx.y;
  const int b  = blockIdx.z;

  __shared__ ushort_t Kt[2][2][4096];  // [kh][buf][key][d] 16B slots, swizzled
  __shared__ ushort_t Vs[2][2][4096];  // [kh][buf][d][key] 16B slots, swizzled

  const int tid  = threadIdx.x;   // 0..255
  const int lane = tid & 63;
  const int w    = tid >> 6;      // wave 0..3
  const int qp   = w & 1;         // q panel within block
  const int kh   = w >> 1;        // key half (0: keys 0..1023, 1: 1024..2047)
  const int ql   = lane & 31;     // q (and A-row / B-col) index
  const int hi   = lane >> 5;     // lane half

  const int q0 = qb * 128 + qp * 64;  // wave owns q0 .. q0+63

  // Q as B operand: bq[qs][ks] = Q[q0+qs*32+ql][ks*16 + hi*8 .. +7]
  short8 bq[2][4];
#pragma unroll
  for (int qs = 0; qs < 2; ++qs) {
    const ushort_t* qp_ =
        Qf + (size_t)(b * NQ + q0 + qs * 32 + ql) * HD + h * HS + hi * 8;
#pragma unroll
    for (int ks = 0; ks < 4; ++ks) bq[qs][ks] = *(const short8*)(qp_ + ks * 16);
  }

  // Staging: wave-pair per kh stages its own tiles; within pair, qp splits
  // rows. Lane covers (row = qp*32 + i*8 + sub, slot); source col
  // pre-swizzled so linear LDS write + XOR read are consistent (rule 21).
  const int sub  = lane >> 3;      // row within 8-row chunk == row & 7
  const int slot = lane & 7;       // 16B slot within row
  const int csrc = slot ^ sub;     // pre-swizzled source column (16B units)
  const ushort_t* kp0 =
      Kf + (size_t)(b * NKK + qp * 32 + sub) * HD + h * HS + csrc * 8;
  const ushort_t* vp0 =
      Vt + (size_t)((b * NH + h) * HS + qp * 32 + sub) * NKK + csrc * 8;

  auto stage = [&](int buf, int kt) {  // kt = GLOBAL tile index
    const ushort_t* kp = kp0 + (size_t)kt * 64 * HD;
    const ushort_t* vp = vp0 + (size_t)kt * 64;
#pragma unroll
    for (int i = 0; i < 4; ++i) {
      __builtin_amdgcn_global_load_lds(
          (const __attribute__((address_space(1))) unsigned*)(kp + (size_t)i * 8 * HD),
          (__attribute__((address_space(3))) unsigned*)(&Kt[kh][buf][(qp * 4 + i) * 512]),
          16, 0, 0);
      __builtin_amdgcn_global_load_lds(
          (const __attribute__((address_space(1))) unsigned*)(vp + (size_t)i * 8 * NKK),
          (__attribute__((address_space(3))) unsigned*)(&Vs[kh][buf][(qp * 4 + i) * 512]),
          16, 0, 0);
    }
  };

  f32x16 o[2][2];  // [qs][ng]
#pragma unroll
  for (int qs = 0; qs < 2; ++qs)
#pragma unroll
    for (int ng = 0; ng < 2; ++ng) o[qs][ng] = (f32x16)0.0f;
  float lsum[2] = {0.0f, 0.0f};

  stage(0, kh * 16);
  __syncthreads();

  for (int t = 0; t < 16; ++t) {
    const int cur = t & 1;
    if (t < 15) stage(cur ^ 1, kh * 16 + t + 1);  // fly during compute
    const ushort_t* kb = &Kt[kh][cur][0];
    const ushort_t* vb = &Vs[kh][cur][0];

#pragma unroll
    for (int kg = 0; kg < 2; ++kg) {
      // S^T = K @ Q^T for both q-subtiles, sharing each K fragment.
      f32x16 s[2];
      s[0] = (f32x16)0.0f;
      s[1] = (f32x16)0.0f;
      const int krow = kg * 32 + ql;
      __builtin_amdgcn_s_setprio(1);
#pragma unroll
      for (int ks = 0; ks < 4; ++ks) {
        short8 ak = *(const short8*)(&kb[krow * 64 + (((ks * 2 + hi) ^ (krow & 7)) * 8)]);
        s[0] = __builtin_amdgcn_mfma_f32_32x32x16_bf16(ak, bq[0][ks], s[0], 0, 0, 0);
        s[1] = __builtin_amdgcn_mfma_f32_32x32x16_bf16(ak, bq[1][ks], s[1], 0, 0, 0);
      }
      __builtin_amdgcn_s_setprio(0);

      // Softmax (no-max, exp2) + in-register repack to PV A-fragments.
      short8 pa[2][2];  // [qs][sp]
#pragma unroll
      for (int qs = 0; qs < 2; ++qs) {
        float p[16];
#pragma unroll
        for (int r = 0; r < 16; ++r) p[r] = __builtin_amdgcn_exp2f(s[qs][r]);
        {
          float a0 = p[0] + p[1], a1 = p[2] + p[3], a2 = p[4] + p[5], a3 = p[6] + p[7];
          float a4 = p[8] + p[9], a5 = p[10] + p[11], a6 = p[12] + p[13], a7 = p[14] + p[15];
          a0 += a1; a2 += a3; a4 += a5; a6 += a7;
          lsum[qs] += (a0 + a2) + (a4 + a6);
        }
#pragma unroll
        for (int sp = 0; sp < 2; ++sp) {
          unsigned wA, wB, wC, wD;
          asm("v_cvt_pk_bf16_f32 %0, %1, %2" : "=v"(wA) : "v"(p[8 * sp + 0]), "v"(p[8 * sp + 1]));
          asm("v_cvt_pk_bf16_f32 %0, %1, %2" : "=v"(wB) : "v"(p[8 * sp + 2]), "v"(p[8 * sp + 3]));
          asm("v_cvt_pk_bf16_f32 %0, %1, %2" : "=v"(wC) : "v"(p[8 * sp + 4]), "v"(p[8 * sp + 5]));
          asm("v_cvt_pk_bf16_f32 %0, %1, %2" : "=v"(wD) : "v"(p[8 * sp + 6]), "v"(p[8 * sp + 7]));
          asm("v_permlane32_swap_b32 %0, %1" : "+v"(wA), "+v"(wC));
          asm("v_permlane32_swap_b32 %0, %1" : "+v"(wB), "+v"(wD));
          u32x4 pw;
          pw.x = wA;  // j0,j1
          pw.y = wB;  // j2,j3
          pw.z = wC;  // j4,j5
          pw.w = wD;  // j6,j7
          pa[qs][sp] = __builtin_bit_cast(short8, pw);
        }
      }

      // O += P @ V : each V fragment feeds both q-subtiles.
      __builtin_amdgcn_s_setprio(1);
#pragma unroll
      for (int sp = 0; sp < 2; ++sp) {
        const int ks = kg * 2 + sp;
#pragma unroll
        for (int ng = 0; ng < 2; ++ng) {
          const int vrow = ng * 32 + ql;
          short8 bv = *(const short8*)(&vb[vrow * 64 + (((ks * 2 + hi) ^ (vrow & 7)) * 8)]);
          o[0][ng] = __builtin_amdgcn_mfma_f32_32x32x16_bf16(pa[0][sp], bv, o[0][ng], 0, 0, 0);
          o[1][ng] = __builtin_amdgcn_mfma_f32_32x32x16_bf16(pa[1][sp], bv, o[1][ng], 0, 0, 0);
        }
      }
      __builtin_amdgcn_s_setprio(0);
    }

    __syncthreads();  // drains vmcnt (next-tile stage) + lgkm, flips buffer
  }

  // Per-wave denominator over this key half: lane + lane^32.
  float ls[2];
#pragma unroll
  for (int qs = 0; qs < 2; ++qs) ls[qs] = lsum[qs] + __shfl_xor(lsum[qs], 32);

  // Cross-kh combine through the (now dead) K/V LDS.
  // S : f32 [2 qp][64 q][64 d] = 32 KB over the Kt region.
  // SL: f32 [2 qp][2 qs][32 ql] partial sums over the Vs region.
  float* S  = (float*)&Kt[0][0][0];
  float* SL = (float*)&Vs[0][0][0];

  if (kh == 1) {
#pragma unroll
    for (int qs = 0; qs < 2; ++qs) {
#pragma unroll
      for (int r = 0; r < 16; ++r) {
        const int qr = (r & 3) + 8 * (r >> 2) + 4 * hi;
        S[(qp * 64 + qs * 32 + qr) * 64 + ql]      = o[qs][0][r];
        S[(qp * 64 + qs * 32 + qr) * 64 + 32 + ql] = o[qs][1][r];
      }
      if (hi == 0) SL[(qp * 2 + qs) * 32 + ql] = ls[qs];
    }
  }
  __syncthreads();
  if (kh == 0) {
    float inv[2];
#pragma unroll
    for (int qs = 0; qs < 2; ++qs)
      inv[qs] = 1.0f / (ls[qs] + SL[(qp * 2 + qs) * 32 + ql]);

    // O layout: row q = (reg&3)+8*(reg>>2)+4*hi, col d = ng*32 + ql.
#pragma unroll
    for (int qs = 0; qs < 2; ++qs)
#pragma unroll
      for (int r = 0; r < 16; ++r) {
        const int qr = (r & 3) + 8 * (r >> 2) + 4 * hi;
        float iv = __shfl(inv[qs], qr);
        const float* srow = &S[(qp * 64 + qs * 32 + qr) * 64];
        size_t base = (size_t)(b * NQ + q0 + qs * 32 + qr) * HD + h * HS + ql;
        CTX[base]      = f2bu((o[qs][0][r] + srow[ql])      * iv);
        CTX[base + 32] = f2bu((o[qs][1][r] + srow[32 + ql]) * iv);
      }
  }
}

// ---------------------------------------------------------------------------
// Kernel 3: out[8192,64] = CTX[8192,512] @ Wh[512,64], LDS-free MFMA.
// ---------------------------------------------------------------------------
__global__ __launch_bounds__(64) void outproj_kernel(
    const ushort_t* __restrict__ CTX, const ushort_t* __restrict__ Wht,
    float* __restrict__ out) {
  const int lane = threadIdx.x & 63;
  const int quad = lane >> 4, c = lane & 15;
  const int m0 = blockIdx.x * 16;

  f32x4 o[4];
#pragma unroll
  for (int n = 0; n < 4; ++n) o[n] = (f32x4)0.0f;

  const ushort_t* arow = CTX + (size_t)(m0 + c) * HD;
#pragma unroll 4
  for (int ks = 0; ks < 16; ++ks) {
    short8 a = *(const short8*)(arow + ks * 32 + quad * 8);
#pragma unroll
    for (int nd = 0; nd < 4; ++nd) {
      short8 bn = *(const short8*)(Wht + (size_t)(nd * 16 + c) * 512 + ks * 32 + quad * 8);
      o[nd] = __builtin_amdgcn_mfma_f32_16x16x32_bf16(a, bn, o[nd], 0, 0, 0);
    }
  }
#pragma unroll
  for (int nd = 0; nd < 4; ++nd)
#pragma unroll
    for (int r = 0; r < 4; ++r)
      out[(size_t)(m0 + quad * 4 + r) * HS + nd * 16 + c] = o[nd][r];
}

// ---------------------------------------------------------------------------
extern "C" void kernel_launch(void* const* d_in, const int* in_sizes, int n_in,
                              void* d_out, int out_size, void* d_ws,
                              size_t ws_size, hipStream_t stream) {
  const float* q  = (const float*)d_in[0];
  const float* k  = (const float*)d_in[1];
  const float* Wq = (const float*)d_in[2];
  const float* Wk = (const float*)d_in[3];
  const float* Wv = (const float*)d_in[4];
  const float* Wh = (const float*)d_in[5];
  float* out = (float*)d_out;

  // Workspace (bf16/ushort): Qf|Kf|Vt|CTX|Vf (each 8 MiB) + Wt (1.5 MiB) + Wht
  const size_t E = (size_t)BB * NQ * HD;
  ushort_t* ws  = (ushort_t*)d_ws;
  ushort_t* Qf  = ws;
  ushort_t* Kf  = Qf + E;
  ushort_t* Vt  = Kf + E;
  ushort_t* CTX = Vt + E;
  ushort_t* Vf  = CTX + E;
  ushort_t* Wt  = Vf + E;                      // 3 x 512 x 512
  ushort_t* Wht = Wt + (size_t)3 * 512 * 512;  // 64 x 512

  wtrans_kernel<<<dim3(8, 8, 4), 256, 0, stream>>>(Wq, Wk, Wv, Wh, Wt, Wht);
  proj_kernel<<<dim3(HD / 128, BB * NQ / 128, 3), 256, 0, stream>>>(
      q, k, Wt, Qf, Kf, Vf);
  vtrans_kernel<<<dim3(NKK / 64, HD / 64, BB), 256, 0, stream>>>(Vf, Vt);
  attn_kernel<<<dim3(NQ / 128, NH, BB), 256, 0, stream>>>(Qf, Kf, Vt, CTX);
  outproj_kernel<<<dim3(BB * NQ / 16), 64, 0, stream>>>(CTX, Wht, out);
}

// Round 6
// 197.279 us; speedup vs baseline: 1.0759x; 1.0759x over previous
//
#include <hip/hip_runtime.h>
#include <hip/hip_bf16.h>

// Problem constants (set_attention): B=4, Nq=Nk=2048, D_IN=512, H=8, HS=64
#define BB   4
#define NQ   2048
#define NKK  2048
#define DIN  512
#define NH   8
#define HS   64
#define HD   512  // NH*HS

typedef __hip_bfloat16 bf16;
typedef unsigned short ushort_t;
typedef __attribute__((ext_vector_type(8))) short short8;   // 8 bf16 (4 VGPRs)
typedef __attribute__((ext_vector_type(4))) float f32x4;    // MFMA 16x16 C/D
typedef __attribute__((ext_vector_type(16))) float f32x16;  // MFMA 32x32 C/D
typedef __attribute__((ext_vector_type(4))) unsigned u32x4;

__device__ __forceinline__ unsigned short f2bu(float x) {
  bf16 h = __float2bfloat16(x);
  return *(unsigned short*)&h;
}

// ---------------------------------------------------------------------------
// Kernel 0: weight transpose + bf16 convert.
// z<3:  W[512k][512n] f32 -> Wt_z[n][k] bf16   (64x64 tiles via LDS)
// z==3: Wh[512k][64n] f32 -> Wht[n][k] bf16
// ---------------------------------------------------------------------------
__global__ __launch_bounds__(256) void wtrans_kernel(
    const float* __restrict__ Wq, const float* __restrict__ Wk,
    const float* __restrict__ Wv, const float* __restrict__ Wh,
    ushort_t* __restrict__ Wt, ushort_t* __restrict__ Wht) {
  const int z = blockIdx.z;
  const float* src;
  ushort_t* dst;
  int S;  // source row length (n-dim)
  if (z < 3) {
    src = (z == 0) ? Wq : (z == 1) ? Wk : Wv;
    dst = Wt + (size_t)z * 512 * 512;
    S = 512;
  } else {
    if (blockIdx.y != 0) return;
    src = Wh;
    dst = Wht;
    S = 64;
  }
  const int k0 = blockIdx.x * 64;
  const int n0 = (z < 3) ? blockIdx.y * 64 : 0;

  __shared__ ushort_t Ls[64 * 72];
  const int tid = threadIdx.x;
  {
    int r = tid >> 2, cb = (tid & 3) * 16;
    const float* sp = src + (size_t)(k0 + r) * S + n0 + cb;
#pragma unroll
    for (int ii = 0; ii < 4; ++ii) {
      float4 f = *(const float4*)(sp + ii * 4);
      __align__(8) ushort_t t4[4] = {f2bu(f.x), f2bu(f.y), f2bu(f.z), f2bu(f.w)};
      *(uint2*)(&Ls[r * 72 + cb + ii * 4]) = *(uint2*)t4;
    }
  }
  __syncthreads();
  {
    int rr = tid >> 2, tb = (tid & 3) * 16;
    __align__(16) ushort_t tmp[16];
#pragma unroll
    for (int j = 0; j < 16; ++j) tmp[j] = Ls[(tb + j) * 72 + rr];
    ushort_t* dp = dst + (size_t)(n0 + rr) * 512 + k0 + tb;
    *(int4*)dp       = ((int4*)tmp)[0];
    *(int4*)(dp + 8) = ((int4*)tmp)[1];
  }
}

// ---------------------------------------------------------------------------
// Kernel 1: QKV projections, bf16 MFMA, double-buffered. Y = X @ W.
// Q is scaled by (1/sqrt(64)) * log2(e) so attention can use exp2 directly.
// ---------------------------------------------------------------------------
__global__ __launch_bounds__(256) void proj_kernel(
    const float* __restrict__ q, const float* __restrict__ k,
    const ushort_t* __restrict__ Wt, ushort_t* __restrict__ Qf,
    ushort_t* __restrict__ Kf, ushort_t* __restrict__ Vf) {
  const int z = blockIdx.z;
  const float* X = (z == 0) ? q : k;
  const ushort_t* Wz = Wt + (size_t)z * 512 * 512;
  ushort_t* Y = (z == 0) ? Qf : (z == 1) ? Kf : Vf;
  // fold 1/sqrt(64) AND log2(e) into Q (attn uses exp2)
  const float sc = (z == 0) ? 0.18033688011112042f : 1.0f;

  __shared__ ushort_t As[2 * 128 * 40];  // [buf][m][k]
  __shared__ ushort_t Bs[2 * 128 * 40];  // [buf][n][k]

  const int tid  = threadIdx.x;
  const int lane = tid & 63;
  const int w    = tid >> 6;
  const int quad = lane >> 4;
  const int c    = lane & 15;
  const int wm   = w >> 1, wn = w & 1;

  const int m0 = blockIdx.y * 128;
  const int n0 = blockIdx.x * 128;
  const int sm  = tid >> 1;
  const int skb = (tid & 1) * 16;

  float4 xa[4];
  int4 wb[2];
  auto load_t = [&](int k0) {
    const float* xp = X + (size_t)(m0 + sm) * DIN + k0 + skb;
    xa[0] = *(const float4*)(xp + 0);
    xa[1] = *(const float4*)(xp + 4);
    xa[2] = *(const float4*)(xp + 8);
    xa[3] = *(const float4*)(xp + 12);
    const ushort_t* wp = Wz + (size_t)(n0 + sm) * 512 + k0 + skb;
    wb[0] = *(const int4*)wp;
    wb[1] = *(const int4*)(wp + 8);
  };
  auto store_t = [&](int buf) {
    __align__(16) ushort_t ta[16];
#pragma unroll
    for (int ii = 0; ii < 4; ++ii) {
      ta[ii * 4 + 0] = f2bu(xa[ii].x);
      ta[ii * 4 + 1] = f2bu(xa[ii].y);
      ta[ii * 4 + 2] = f2bu(xa[ii].z);
      ta[ii * 4 + 3] = f2bu(xa[ii].w);
    }
    *(int4*)(&As[buf * 5120 + sm * 40 + skb])     = ((int4*)ta)[0];
    *(int4*)(&As[buf * 5120 + sm * 40 + skb + 8]) = ((int4*)ta)[1];
    *(int4*)(&Bs[buf * 5120 + sm * 40 + skb])     = wb[0];
    *(int4*)(&Bs[buf * 5120 + sm * 40 + skb + 8]) = wb[1];
  };

  f32x4 acc[4][4];
#pragma unroll
  for (int m = 0; m < 4; ++m)
#pragma unroll
    for (int n = 0; n < 4; ++n) acc[m][n] = (f32x4)0.0f;

  load_t(0);
  store_t(0);
  __syncthreads();

  for (int t = 0; t < 16; ++t) {
    const int cur = t & 1;
    if (t < 15) load_t((t + 1) * 32);
    const ushort_t* as = As + cur * 5120;
    const ushort_t* bs = Bs + cur * 5120;
    short8 af[4], bfr[4];
#pragma unroll
    for (int m = 0; m < 4; ++m)
      af[m] = *(const short8*)(&as[(wm * 64 + m * 16 + c) * 40 + quad * 8]);
#pragma unroll
    for (int n = 0; n < 4; ++n)
      bfr[n] = *(const short8*)(&bs[(wn * 64 + n * 16 + c) * 40 + quad * 8]);
#pragma unroll
    for (int m = 0; m < 4; ++m)
#pragma unroll
      for (int n = 0; n < 4; ++n)
        acc[m][n] = __builtin_amdgcn_mfma_f32_16x16x32_bf16(af[m], bfr[n], acc[m][n], 0, 0, 0);
    if (t < 15) store_t(cur ^ 1);
    __syncthreads();
  }

#pragma unroll
  for (int m = 0; m < 4; ++m)
#pragma unroll
    for (int n = 0; n < 4; ++n)
#pragma unroll
      for (int r = 0; r < 4; ++r) {
        int row = m0 + wm * 64 + m * 16 + quad * 4 + r;
        int col = n0 + wn * 64 + n * 16 + c;
        Y[(size_t)row * HD + col] = f2bu(acc[m][n][r] * sc);
      }
}

// ---------------------------------------------------------------------------
// Kernel 1b: V transpose. Vf[(b*2048+t)*512 + cc] -> Vt[(b*512+cc)*2048 + t].
// ---------------------------------------------------------------------------
__global__ __launch_bounds__(256) void vtrans_kernel(
    const ushort_t* __restrict__ Vf, ushort_t* __restrict__ Vt) {
  const int b  = blockIdx.z;
  const int t0 = blockIdx.x * 64;
  const int c0 = blockIdx.y * 64;
  __shared__ ushort_t Ls[64 * 72];
  const int tid = threadIdx.x;
  {
    int r = tid >> 2, cb = (tid & 3) * 16;
    const ushort_t* src = Vf + (size_t)(b * NQ + t0 + r) * HD + c0 + cb;
    *(int4*)(&Ls[r * 72 + cb])     = *(const int4*)src;
    *(int4*)(&Ls[r * 72 + cb + 8]) = *(const int4*)(src + 8);
  }
  __syncthreads();
  {
    int rr = tid >> 2, tb = (tid & 3) * 16;
    __align__(16) ushort_t tmp[16];
#pragma unroll
    for (int j = 0; j < 16; ++j) tmp[j] = Ls[(tb + j) * 72 + rr];
    ushort_t* dst = Vt + (size_t)(b * HD + c0 + rr) * NKK + t0 + tb;
    *(int4*)dst       = ((int4*)tmp)[0];
    *(int4*)(dst + 8) = ((int4*)tmp)[1];
  }
}

// ---------------------------------------------------------------------------
// Kernel 2: MFMA flash attention, v7 = v5 + XCD-aware block swizzle.
//  - v5 structure (measured 65.5 us): 2 waves/block, 64 q/wave (2 q-subtiles
//    of 32), 32 KB LDS, each K/V fragment feeds two MFMAs.
//  - NEW: 1D grid of 512 blocks; id -> (panel, qb) such that each XCD
//    (id & 7 under round-robin dispatch) owns 4 consecutive (b,h) panels and
//    ALL 16 qb-blocks of each panel. Per-XCD K/V working set = 4 panels x
//    512 KB = 2 MB <= 4 MB L2, so K/V is HBM-fetched once per panel and
//    L2-hit afterwards (was: scattered -> 16 MB working set -> L2 thrash,
//    ~4x HBM re-fetch, 900-cyc latency stalls at 1 wave/SIMD).
//  - K/V via global_load_lds, linear dest + pre-swizzled source column;
//    reads use slot ^ (row&7) (rule 21).
//  - Softmax p = 2^s via __builtin_amdgcn_exp2f (log2e folded into Q scale).
//  - P -> PV A-frag via v_cvt_pk_bf16_f32 + v_permlane32_swap_b32 (T12).
// ---------------------------------------------------------------------------
__global__ __launch_bounds__(128) void attn_kernel(
    const ushort_t* __restrict__ Qf, const ushort_t* __restrict__ Kf,
    const ushort_t* __restrict__ Vt, ushort_t* __restrict__ CTX) {
  // XCD-aware decode: 512 blocks, xcd = id & 7 (round-robin heuristic).
  // Panel p = b*8+h in [0,32); each xcd owns panels [xcd*4, xcd*4+4).
  const int id   = blockIdx.x;
  const int xcd  = id & 7;
  const int slot = id >> 3;             // 0..63 within xcd
  const int p    = xcd * 4 + (slot >> 4);  // panel
  const int qb   = slot & 15;
  const int h    = p & 7;
  const int b    = p >> 3;

  __shared__ ushort_t Kt[2 * 64 * 64];  // [buf][key][d] 16B slots, swizzled
  __shared__ ushort_t Vs[2 * 64 * 64];  // [buf][d][key] 16B slots, swizzled

  const int tid  = threadIdx.x;   // 0..127
  const int lane = tid & 63;
  const int w    = tid >> 6;      // wave 0..1
  const int ql   = lane & 31;     // q (and A-row / B-col) index
  const int hi   = lane >> 5;     // lane half

  const int q0 = qb * 128 + w * 64;  // wave owns q0 .. q0+63

  // Q as B operand: bq[qs][ks] = Q[q0+qs*32+ql][ks*16 + hi*8 .. +7]
  short8 bq[2][4];
#pragma unroll
  for (int qs = 0; qs < 2; ++qs) {
    const ushort_t* qp =
        Qf + (size_t)(b * NQ + q0 + qs * 32 + ql) * HD + h * HS + hi * 8;
#pragma unroll
    for (int ks = 0; ks < 4; ++ks) bq[qs][ks] = *(const short8*)(qp + ks * 16);
  }

  // Staging: per-wave 4 chunks of 8 rows x 64 cols each for K and V.
  const int sub  = lane >> 3;      // row within 8-row chunk == row & 7
  const int slt  = lane & 7;       // 16B slot within row
  const int csrc = slt ^ sub;      // pre-swizzled source column (16B units)
  const ushort_t* kp0 =
      Kf + (size_t)(b * NKK + w * 32 + sub) * HD + h * HS + csrc * 8;
  const ushort_t* vp0 =
      Vt + (size_t)((b * NH + h) * HS + w * 32 + sub) * NKK + csrc * 8;

  auto stage = [&](int buf, int kt) {
    const ushort_t* kp = kp0 + (size_t)kt * 64 * HD;
    const ushort_t* vp = vp0 + (size_t)kt * 64;
#pragma unroll
    for (int i = 0; i < 4; ++i) {
      __builtin_amdgcn_global_load_lds(
          (const __attribute__((address_space(1))) unsigned*)(kp + (size_t)i * 8 * HD),
          (__attribute__((address_space(3))) unsigned*)(&Kt[buf * 4096 + (w * 4 + i) * 512]),
          16, 0, 0);
      __builtin_amdgcn_global_load_lds(
          (const __attribute__((address_space(1))) unsigned*)(vp + (size_t)i * 8 * NKK),
          (__attribute__((address_space(3))) unsigned*)(&Vs[buf * 4096 + (w * 4 + i) * 512]),
          16, 0, 0);
    }
  };

  f32x16 o[2][2];  // [qs][ng]
#pragma unroll
  for (int qs = 0; qs < 2; ++qs)
#pragma unroll
    for (int ng = 0; ng < 2; ++ng) o[qs][ng] = (f32x16)0.0f;
  float lsum[2] = {0.0f, 0.0f};

  stage(0, 0);
  __syncthreads();

  for (int kt = 0; kt < NKK / 64; ++kt) {
    const int cur = kt & 1;
    if (kt < NKK / 64 - 1) stage(cur ^ 1, kt + 1);  // fly during compute
    const ushort_t* kb = &Kt[cur * 4096];
    const ushort_t* vb = &Vs[cur * 4096];

#pragma unroll
    for (int kg = 0; kg < 2; ++kg) {
      // S^T = K @ Q^T for both q-subtiles, sharing each K fragment.
      f32x16 s[2];
      s[0] = (f32x16)0.0f;
      s[1] = (f32x16)0.0f;
      const int krow = kg * 32 + ql;
      __builtin_amdgcn_s_setprio(1);
#pragma unroll
      for (int ks = 0; ks < 4; ++ks) {
        short8 ak = *(const short8*)(&kb[krow * 64 + (((ks * 2 + hi) ^ (krow & 7)) * 8)]);
        s[0] = __builtin_amdgcn_mfma_f32_32x32x16_bf16(ak, bq[0][ks], s[0], 0, 0, 0);
        s[1] = __builtin_amdgcn_mfma_f32_32x32x16_bf16(ak, bq[1][ks], s[1], 0, 0, 0);
      }
      __builtin_amdgcn_s_setprio(0);

      // Softmax (no-max, exp2) + in-register repack to PV A-fragments.
      short8 pa[2][2];  // [qs][sp]
#pragma unroll
      for (int qs = 0; qs < 2; ++qs) {
        float p_[16];
#pragma unroll
        for (int r = 0; r < 16; ++r) p_[r] = __builtin_amdgcn_exp2f(s[qs][r]);
        {
          float a0 = p_[0] + p_[1], a1 = p_[2] + p_[3], a2 = p_[4] + p_[5], a3 = p_[6] + p_[7];
          float a4 = p_[8] + p_[9], a5 = p_[10] + p_[11], a6 = p_[12] + p_[13], a7 = p_[14] + p_[15];
          a0 += a1; a2 += a3; a4 += a5; a6 += a7;
          lsum[qs] += (a0 + a2) + (a4 + a6);
        }
#pragma unroll
        for (int sp = 0; sp < 2; ++sp) {
          unsigned wA, wB, wC, wD;
          asm("v_cvt_pk_bf16_f32 %0, %1, %2" : "=v"(wA) : "v"(p_[8 * sp + 0]), "v"(p_[8 * sp + 1]));
          asm("v_cvt_pk_bf16_f32 %0, %1, %2" : "=v"(wB) : "v"(p_[8 * sp + 2]), "v"(p_[8 * sp + 3]));
          asm("v_cvt_pk_bf16_f32 %0, %1, %2" : "=v"(wC) : "v"(p_[8 * sp + 4]), "v"(p_[8 * sp + 5]));
          asm("v_cvt_pk_bf16_f32 %0, %1, %2" : "=v"(wD) : "v"(p_[8 * sp + 6]), "v"(p_[8 * sp + 7]));
          asm("v_permlane32_swap_b32 %0, %1" : "+v"(wA), "+v"(wC));
          asm("v_permlane32_swap_b32 %0, %1" : "+v"(wB), "+v"(wD));
          u32x4 pw;
          pw.x = wA;  // j0,j1
          pw.y = wB;  // j2,j3
          pw.z = wC;  // j4,j5
          pw.w = wD;  // j6,j7
          pa[qs][sp] = __builtin_bit_cast(short8, pw);
        }
      }

      // O += P @ V : each V fragment feeds both q-subtiles.
      __builtin_amdgcn_s_setprio(1);
#pragma unroll
      for (int sp = 0; sp < 2; ++sp) {
        const int ks = kg * 2 + sp;
#pragma unroll
        for (int ng = 0; ng < 2; ++ng) {
          const int vrow = ng * 32 + ql;
          short8 bv = *(const short8*)(&vb[vrow * 64 + (((ks * 2 + hi) ^ (vrow & 7)) * 8)]);
          o[0][ng] = __builtin_amdgcn_mfma_f32_32x32x16_bf16(pa[0][sp], bv, o[0][ng], 0, 0, 0);
          o[1][ng] = __builtin_amdgcn_mfma_f32_32x32x16_bf16(pa[1][sp], bv, o[1][ng], 0, 0, 0);
        }
      }
      __builtin_amdgcn_s_setprio(0);
    }

    __syncthreads();  // drains vmcnt (next-tile stage) + lgkm, flips buffer
  }

  // Denominator: lane + lane^32 cover all 2048 keys of column q.
  float inv[2];
#pragma unroll
  for (int qs = 0; qs < 2; ++qs) {
    float tot = lsum[qs] + __shfl_xor(lsum[qs], 32);
    inv[qs] = 1.0f / tot;
  }

  // O layout: row q = (reg&3)+8*(reg>>2)+4*hi, col d = ng*32 + ql.
#pragma unroll
  for (int qs = 0; qs < 2; ++qs)
#pragma unroll
    for (int r = 0; r < 16; ++r) {
      int qr = (r & 3) + 8 * (r >> 2) + 4 * hi;
      float iv = __shfl(inv[qs], qr);
      size_t base = (size_t)(b * NQ + q0 + qs * 32 + qr) * HD + h * HS + ql;
      CTX[base]      = f2bu(o[qs][0][r] * iv);
      CTX[base + 32] = f2bu(o[qs][1][r] * iv);
    }
}

// ---------------------------------------------------------------------------
// Kernel 3: out[8192,64] = CTX[8192,512] @ Wh[512,64], LDS-free MFMA.
// ---------------------------------------------------------------------------
__global__ __launch_bounds__(64) void outproj_kernel(
    const ushort_t* __restrict__ CTX, const ushort_t* __restrict__ Wht,
    float* __restrict__ out) {
  const int lane = threadIdx.x & 63;
  const int quad = lane >> 4, c = lane & 15;
  const int m0 = blockIdx.x * 16;

  f32x4 o[4];
#pragma unroll
  for (int n = 0; n < 4; ++n) o[n] = (f32x4)0.0f;

  const ushort_t* arow = CTX + (size_t)(m0 + c) * HD;
#pragma unroll 4
  for (int ks = 0; ks < 16; ++ks) {
    short8 a = *(const short8*)(arow + ks * 32 + quad * 8);
#pragma unroll
    for (int nd = 0; nd < 4; ++nd) {
      short8 bn = *(const short8*)(Wht + (size_t)(nd * 16 + c) * 512 + ks * 32 + quad * 8);
      o[nd] = __builtin_amdgcn_mfma_f32_16x16x32_bf16(a, bn, o[nd], 0, 0, 0);
    }
  }
#pragma unroll
  for (int nd = 0; nd < 4; ++nd)
#pragma unroll
    for (int r = 0; r < 4; ++r)
      out[(size_t)(m0 + quad * 4 + r) * HS + nd * 16 + c] = o[nd][r];
}

// ---------------------------------------------------------------------------
extern "C" void kernel_launch(void* const* d_in, const int* in_sizes, int n_in,
                              void* d_out, int out_size, void* d_ws,
                              size_t ws_size, hipStream_t stream) {
  const float* q  = (const float*)d_in[0];
  const float* k  = (const float*)d_in[1];
  const float* Wq = (const float*)d_in[2];
  const float* Wk = (const float*)d_in[3];
  const float* Wv = (const float*)d_in[4];
  const float* Wh = (const float*)d_in[5];
  float* out = (float*)d_out;

  // Workspace (bf16/ushort): Qf|Kf|Vt|CTX|Vf (each 8 MiB) + Wt (1.5 MiB) + Wht
  const size_t E = (size_t)BB * NQ * HD;
  ushort_t* ws  = (ushort_t*)d_ws;
  ushort_t* Qf  = ws;
  ushort_t* Kf  = Qf + E;
  ushort_t* Vt  = Kf + E;
  ushort_t* CTX = Vt + E;
  ushort_t* Vf  = CTX + E;
  ushort_t* Wt  = Vf + E;                      // 3 x 512 x 512
  ushort_t* Wht = Wt + (size_t)3 * 512 * 512;  // 64 x 512

  wtrans_kernel<<<dim3(8, 8, 4), 256, 0, stream>>>(Wq, Wk, Wv, Wh, Wt, Wht);
  proj_kernel<<<dim3(HD / 128, BB * NQ / 128, 3), 256, 0, stream>>>(
      q, k, Wt, Qf, Kf, Vf);
  vtrans_kernel<<<dim3(NKK / 64, HD / 64, BB), 256, 0, stream>>>(Vf, Vt);
  attn_kernel<<<dim3(16 * NH * BB), 128, 0, stream>>>(Qf, Kf, Vt, CTX);
  outproj_kernel<<<dim3(BB * NQ / 16), 64, 0, stream>>>(CTX, Wht, out);
}